// Round 9
// baseline (159.780 us; speedup 1.0000x reference)
//
#include <hip/hip_runtime.h>

// Bidirectional GRU (H=32, input=1, B=2048, T=512) + MLP head, fully fused.
//
// Reference takes out[:, -1, :] = concat(h_fwd after T steps, h_bwd after ONE
// step from h0=0 on x[T-1]) -> only the forward scan is sequential; W_hh_b is
// entirely unused.
//
// R20 = R19 (95.5 us, MFMA recurrence, h in A / W in B, 1 el/lane epilogue)
// with the LDS h-exchange replaced by a REGISTER crossbar exchange.
//
// Governing law (R13..R19): this problem is pure latency. 2048 independent
// rows -> wall = 512 steps x per-step chain, regardless of wave packing.
// R19 chain 447 = epilogue(~90) + LDS round-trip(~140) + MFMA(~30) + misc.
// The LDS round-trip is the biggest removable term.
//
// Register exchange (new):
//   * Only A-rows m in {0,4,8,12} are consumed (D reg0 -> m=4q), i.e. only
//     lanes with nh in {0,4,8,12} need correct A-frags; uniform construction.
//   * Post-epilogue distribution: for fixed nh, lanes {nh, nh+16, nh+32,
//     nh+48} hold h[0][nh], h[1][nh], h[0][nh+16], h[1][nh+16]. So:
//       cvt_f16 (rne) -> permlane32_swap (pair col/col+16 of same row)
//       -> v_pack_b32_f16: P(l<32) = pk(h[p][c], h[p][c+16]), p=l>>4, c=l&15
//       -> 4x ds_bpermute_b32 from src lanes R*16+4q+i (loop-invariant
//          addrs; R=(l>>2)&1 matches row ownership row(4s)=s&1).
//   * K-labeling freedom: B is loaded PAIR-INTERLEAVED (k order: 4q, 4q+16,
//     4q+1, 4q+17, ...) so the 4 gathered pairs ARE the A-frag -- zero
//     rearrangement. (Labeling consistent A<->B; proven mechanism R16/R19.)
//   * No ds_write / wave_barrier / LDS visibility in the loop; hbuf deleted.
//   * Epilogue tail shaved: zh = z*h and omz = 1-z computed EARLY (z ready
//     in parallel with r); h = fma(omz, nn, zh) -- one fma after nn.
//
// Kept from R19: 6 MFMA (3 gates x 2 j-halves), hsel select, seeds in C reg0
// and per-lane VALU, exp2-domain folding, x staged in LDS vf4/4-steps,
// backward single step + MLP head. 256 blocks x 256 thr, 1 wave/SIMD.

typedef float vf4 __attribute__((ext_vector_type(4)));
typedef int   vi4 __attribute__((ext_vector_type(4)));
typedef _Float16 f16;
typedef f16 h8 __attribute__((ext_vector_type(8)));

#define TT 512
#define HH 32

#define LOG2E 1.44269504f

__device__ __forceinline__ float fast_sigm(float a) {   // sigmoid(a)
  return __builtin_amdgcn_rcpf(1.0f + __builtin_amdgcn_exp2f(-LOG2E * a));
}
__device__ __forceinline__ float fast_tanh(float a) {   // tanh(a)
  return __builtin_fmaf(-2.0f,
      __builtin_amdgcn_rcpf(1.0f + __builtin_amdgcn_exp2f(2.0f * LOG2E * a)),
      1.0f);
}

__global__ __launch_bounds__(256)
__attribute__((amdgpu_waves_per_eu(1, 1)))
void gru_bidir_head(const float* __restrict__ X,
                    const float* __restrict__ Wih_f, const float* __restrict__ Whh_f,
                    const float* __restrict__ bih_f, const float* __restrict__ bhh_f,
                    const float* __restrict__ Wih_b,
                    const float* __restrict__ bih_b, const float* __restrict__ bhh_b,
                    const float* __restrict__ W1, const float* __restrict__ b1,
                    const float* __restrict__ W2, const float* __restrict__ b2,
                    float* __restrict__ out)
{
  __shared__ float xbuf[8][TT];        // staged input rows (16 KB)
  __shared__ float obuf[8][64];        // [row][h_f(32) | h_b(32)] (2 KB)

  const int tid  = threadIdx.x;
  const int lane = tid & 63;
  const int wid  = tid >> 6;           // wave 0..3; serves block rows {2wid, 2wid+1}
  const int nh   = lane & 15;          // MFMA n-index
  const int q    = lane >> 4;          // quad 0..3
  const int p    = q & 1;              // owned element's row parity
  const int hsel = lane >> 5;          // owned element's j-half
  const int j    = nh + 16 * hsel;     // owned output column
  const int rs   = 2 * wid + p;        // owned element's local row (0..7)

  // --- stage 8 rows of X into LDS (32-lane groups, coalesced) ---
  const int g32 = tid & 31, rsS = tid >> 5;
  const vf4* Xr4 = (const vf4*)(X + (size_t)((blockIdx.x << 3) + rsS) * TT);
  vf4* xb4 = (vf4*)&xbuf[rsS][0];
  #pragma unroll
  for (int qq = 0; qq < 4; ++qq) xb4[g32 + 32 * qq] = Xr4[g32 + 32 * qq];

  const float s1 = -LOG2E;             // r,z: sigmoid domain (negated)
  const float s2 = 2.0f * LOG2E;       // n: tanh domain

  // --- B-fragments: W_hh, constant, PAIR-INTERLEAVED labeling:
  //     element order k = (4q, 16+4q, 4q+1, 16+4q+1, 4q+2, 16+4q+2, 4q+3, 16+4q+3)
  //     Gate G, j-half F: lane (nh,q) holds W[G*32 + nh + 16F][k] * S ---
#define LDB(P, G, F, S) h8 P; { \
    const float* wr = Whh_f + (size_t)((G)*HH + nh + 16*(F)) * HH; \
    const int k1 = 4*q, k2 = 16 + 4*q; \
    P = (h8){ (f16)(wr[k1  ]*(S)), (f16)(wr[k2  ]*(S)), \
              (f16)(wr[k1+1]*(S)), (f16)(wr[k2+1]*(S)), \
              (f16)(wr[k1+2]*(S)), (f16)(wr[k2+2]*(S)), \
              (f16)(wr[k1+3]*(S)), (f16)(wr[k2+3]*(S)) }; }
  LDB(Br0, 0, 0, s1); LDB(Br1, 0, 1, s1);
  LDB(Bz0, 1, 0, s1); LDB(Bz1, 1, 1, s1);
  LDB(Bn0, 2, 0, s2); LDB(Bn1, 2, 1, s2);

  // --- per-lane seed consts for the owned column j ---
  const float xwr = Wih_f[j] * s1, xwz = Wih_f[HH + j] * s1, xwn = Wih_f[2*HH + j] * s2;
  const float cbr = (bih_f[j]      + bhh_f[j])      * s1;
  const float cbz = (bih_f[HH + j] + bhh_f[HH + j]) * s1;
  const float cbn = bih_f[2*HH + j] * s2;        // n: b_ih term (with x)
  const float cbh = bhh_f[2*HH + j] * s2;        // n: b_hh term (inside r*(.)) -> C
  const vf4 Ch = { cbh, 0.0f, 0.0f, 0.0f };

  // --- bpermute gather addresses (loop-invariant): A-frag of lane l reads
  //     packed pairs P from src lanes R*16 + 4q + i, R=(l>>2)&1, i=0..3.
  //     (Only lanes nh in {0,4,8,12} feed consumed A-rows; uniform is fine.)
  const int lsrc4 = ((((lane >> 2) & 1) << 4) + ((lane >> 4) << 2)) << 2;  // bytes

  float h = 0.0f;
  h8 A = {};                                     // h0 = 0
  const vf4* xv = (const vf4*)&xbuf[rs][0];
  vf4 x4 = xv[0];

  #pragma unroll 1
  for (int tg = 0; tg < TT / 4; ++tg) {
    const vf4 x4n = xv[tg + 1 < TT / 4 ? tg + 1 : tg];   // off critical path

    // hoist x-dependent seeds for the 4 sub-steps (own row's x, own j)
    const float sr0 = __builtin_fmaf(x4.x, xwr, cbr), sz0 = __builtin_fmaf(x4.x, xwz, cbz),
                sn0 = __builtin_fmaf(x4.x, xwn, cbn);
    const float sr1 = __builtin_fmaf(x4.y, xwr, cbr), sz1 = __builtin_fmaf(x4.y, xwz, cbz),
                sn1 = __builtin_fmaf(x4.y, xwn, cbn);
    const float sr2 = __builtin_fmaf(x4.z, xwr, cbr), sz2 = __builtin_fmaf(x4.z, xwz, cbz),
                sn2 = __builtin_fmaf(x4.z, xwn, cbn);
    const float sr3 = __builtin_fmaf(x4.w, xwr, cbr), sz3 = __builtin_fmaf(x4.w, xwz, cbz),
                sn3 = __builtin_fmaf(x4.w, xwn, cbn);

    #pragma unroll
    for (int u = 0; u < 4; ++u) {
      const float sr = (u == 0) ? sr0 : (u == 1) ? sr1 : (u == 2) ? sr2 : sr3;
      const float sz = (u == 0) ? sz0 : (u == 1) ? sz1 : (u == 2) ? sz2 : sz3;
      const float sn = (u == 0) ? sn0 : (u == 1) ? sn1 : (u == 2) ? sn2 : sn3;

      // D = h @ W^T (+ per-lane seeds in C reg0): 6 MFMA, reg0 consumed
      const vf4 Cr = { sr, 0.0f, 0.0f, 0.0f };
      const vf4 Cz = { sz, 0.0f, 0.0f, 0.0f };
      const vf4 Dr0 = __builtin_amdgcn_mfma_f32_16x16x32_f16(A, Br0, Cr, 0, 0, 0);
      const vf4 Dr1 = __builtin_amdgcn_mfma_f32_16x16x32_f16(A, Br1, Cr, 0, 0, 0);
      const vf4 Dz0 = __builtin_amdgcn_mfma_f32_16x16x32_f16(A, Bz0, Cz, 0, 0, 0);
      const vf4 Dz1 = __builtin_amdgcn_mfma_f32_16x16x32_f16(A, Bz1, Cz, 0, 0, 0);
      const vf4 Dn0 = __builtin_amdgcn_mfma_f32_16x16x32_f16(A, Bn0, Ch, 0, 0, 0);
      const vf4 Dn1 = __builtin_amdgcn_mfma_f32_16x16x32_f16(A, Bn1, Ch, 0, 0, 0);

      // select own j-half: element (row p, col j), seeds already included
      const float ar = hsel ? Dr1[0] : Dr0[0];
      const float az = hsel ? Dz1[0] : Dz0[0];
      const float an = hsel ? Dn1[0] : Dn0[0];

      // epilogue: ONE element per lane; z-path precomputed early so only one
      // fma follows nn on the critical chain
      const float z   = __builtin_amdgcn_rcpf(1.0f + __builtin_amdgcn_exp2f(az));
      const float zh  = z * h;
      const float omz = 1.0f - z;
      const float r   = __builtin_amdgcn_rcpf(1.0f + __builtin_amdgcn_exp2f(ar));
      const float y   = __builtin_fmaf(r, an, sn);
      const float nn  = __builtin_fmaf(-2.0f,
          __builtin_amdgcn_rcpf(1.0f + __builtin_amdgcn_exp2f(y)), 1.0f);
      h = __builtin_fmaf(omz, nn, zh);           // (1-z)*n + z*h

      // --- register exchange: h -> next A-frag (no LDS) ---
      unsigned hf;
      asm("v_cvt_f16_f32 %0, %1" : "=v"(hf) : "v"(h));       // rne, low 16b
      unsigned plo = hf, phi = hf;
      asm volatile("v_permlane32_swap_b32 %0, %1" : "+v"(plo), "+v"(phi));
      // plo(l) = hf(l&31) [own col c], phi(l) = hf(32|(l&31)) [col c+16]
      unsigned P;
      asm("v_pack_b32_f16 %0, %1, %2" : "=v"(P) : "v"(plo), "v"(phi));
      // P(l<32) = pk(h[p][c], h[p][c+16]);  gather 4 pairs = A-frag
      const int a0 = __builtin_amdgcn_ds_bpermute(lsrc4,      (int)P);
      const int a1 = __builtin_amdgcn_ds_bpermute(lsrc4 + 4,  (int)P);
      const int a2 = __builtin_amdgcn_ds_bpermute(lsrc4 + 8,  (int)P);
      const int a3 = __builtin_amdgcn_ds_bpermute(lsrc4 + 12, (int)P);
      union { vi4 i; h8 v; } ua;
      ua.i = (vi4){a0, a1, a2, a3};
      A = ua.v;
    }
    x4 = x4n;
  }

  // --- publish h_f (fp32): each lane writes its (row, j) element once ---
  obuf[rs][j] = h;
  __syncthreads();

  // --- backward direction: exactly ONE GRU step from h0=0 on x[T-1] ---
  const float xl  = xbuf[rsS][TT - 1];
  const float rbv = fast_sigm(__builtin_fmaf(xl, Wih_b[g32],      bih_b[g32]      + bhh_b[g32]));
  const float zbv = fast_sigm(__builtin_fmaf(xl, Wih_b[HH + g32], bih_b[HH + g32] + bhh_b[HH + g32]));
  const float xnb = __builtin_fmaf(xl, Wih_b[2*HH + g32], bih_b[2*HH + g32]);
  const float nbv = fast_tanh(__builtin_fmaf(rbv, bhh_b[2*HH + g32], xnb));
  const float hbv = nbv - zbv * nbv;             // (1-zb)*nb + zb*0

  obuf[rsS][32 + g32] = hbv;                     // h_b
  __builtin_amdgcn_wave_barrier();

  // --- MLP head: sigmoid(W2 @ relu(W1 @ [h_f,h_b] + b1) + b2) ---
  const int jj = g32 & 15;                       // lanes 16..31 duplicate
  const vf4* W1r = (const vf4*)(W1 + jj * 64);
  const vf4* hc  = (const vf4*)&obuf[rsS][0];
  vf4 a4 = W1r[0] * hc[0];
  #pragma unroll
  for (int qq = 1; qq < 16; ++qq)
    a4 = __builtin_elementwise_fma(W1r[qq], hc[qq], a4);
  float acc = b1[jj] + (a4.x + a4.y) + (a4.z + a4.w);
  float h1v = fmaxf(acc, 0.0f) * W2[jj];
  h1v += __shfl_down(h1v, 8, 16);
  h1v += __shfl_down(h1v, 4, 16);
  h1v += __shfl_down(h1v, 2, 16);
  h1v += __shfl_down(h1v, 1, 16);
  if (g32 == 0) out[(blockIdx.x << 3) + rsS] = fast_sigm(h1v + b2[0]);
}

extern "C" void kernel_launch(void* const* d_in, const int* in_sizes, int n_in,
                              void* d_out, int out_size, void* d_ws, size_t ws_size,
                              hipStream_t stream) {
  const float* X     = (const float*)d_in[0];
  const float* Wih_f = (const float*)d_in[1];
  const float* Whh_f = (const float*)d_in[2];
  const float* bih_f = (const float*)d_in[3];
  const float* bhh_f = (const float*)d_in[4];
  const float* Wih_b = (const float*)d_in[5];
  // d_in[6] = W_hh_b: unused — backward direction runs exactly one step from h0=0.
  const float* bih_b = (const float*)d_in[7];
  const float* bhh_b = (const float*)d_in[8];
  const float* W1    = (const float*)d_in[9];
  const float* b1    = (const float*)d_in[10];
  const float* W2    = (const float*)d_in[11];
  const float* b2    = (const float*)d_in[12];
  float* out = (float*)d_out;

  // 2048 rows / 8 rows per 256-thread block = 256 blocks = 1 block/CU,
  // 1024 independent waves = 1 wave/SIMD, full chip. No LDS (and no barrier
  // of any kind) in the recurrence loop: exchange is a register crossbar.
  gru_bidir_head<<<256, 256, 0, stream>>>(X, Wih_f, Whh_f, bih_f, bhh_f,
                                          Wih_b, bih_b, bhh_b, W1, b1, W2, b2, out);
}

// Round 10
// 150.858 us; speedup vs baseline: 1.0591x; 1.0591x over previous
//
#include <hip/hip_runtime.h>

// Bidirectional GRU (H=32, input=1, B=2048, T=512) + MLP head, fully fused.
//
// Reference takes out[:, -1, :] = concat(h_fwd after T steps, h_bwd after ONE
// step from h0=0 on x[T-1]) -> only the forward scan is sequential; W_hh_b is
// entirely unused.
//
// R21 = R19 (best: 95.5 us rocprof; MFMA recurrence h-in-A / W-in-B, 1
// element/lane epilogue, wave-internal LDS exchange) with the chain polished:
//
//   * Governing law (R13..R20): latency-bound. wall = 512 x per-step chain;
//     wave packing irrelevant. R20 proved bpermute >= LDS for the exchange.
//   * MfmaUtil 21% x 447 => each 16x16x32 MFMA ~16 SIMD-cyc; 6-MFMA block
//     ~110 cyc on chain. 6 MFMAs is a hard floor (96 gate-outputs, n=16;
//     gate/j cannot ride A's m-dim). Chain floor ~350; R19 measured 447.
//   * NEW pair-layout exchange: packed-pair LDS buffer
//       hp[parity][wave][row][col] (u32) = (h[row][c], h[row][c+16])
//     Write: each lane ONE ds_write_b16 at (p, nh, hsel). Read: ONE
//     ds_read_b128 at (R=(lane>>2)&1, 4q) = the A-frag directly (B is loaded
//     pair-interleaved, R20's proven labeling) -- replaces 2x ds_read_b64 +
//     register assembly. Read addrs R*64+q*16 B: all 32 banks once ->
//     conflict-free. Parity dbuf; addresses compile-time via unrolled u.
//   * NEW fused epilogue tail: base = fma(z,h,1-z), m2 = 2z-2 computed right
//     after z (parallel with r-path); h = fma(m2, w, base) -- ONE fma after
//     the last rcp (was: nn-fma + h-fma serial).
//   * Everything else identical to R19: 6 MFMA (3 gates x 2 j-halves), hsel
//     cndmask select, seeds ride C reg0 + per-lane VALU, exp2-domain folding,
//     x staged in LDS vf4/4-steps, backward 1-step + MLP head.
//     256 blocks x 256 thr = 1024 independent waves = 1 wave/SIMD, full chip.

typedef float vf4 __attribute__((ext_vector_type(4)));
typedef _Float16 f16;
typedef f16 h8 __attribute__((ext_vector_type(8)));

#define TT 512
#define HH 32

#define LOG2E 1.44269504f

__device__ __forceinline__ float fast_sigm(float a) {   // sigmoid(a)
  return __builtin_amdgcn_rcpf(1.0f + __builtin_amdgcn_exp2f(-LOG2E * a));
}
__device__ __forceinline__ float fast_tanh(float a) {   // tanh(a)
  return __builtin_fmaf(-2.0f,
      __builtin_amdgcn_rcpf(1.0f + __builtin_amdgcn_exp2f(2.0f * LOG2E * a)),
      1.0f);
}

__global__ __launch_bounds__(256)
__attribute__((amdgpu_waves_per_eu(1, 1)))
void gru_bidir_head(const float* __restrict__ X,
                    const float* __restrict__ Wih_f, const float* __restrict__ Whh_f,
                    const float* __restrict__ bih_f, const float* __restrict__ bhh_f,
                    const float* __restrict__ Wih_b,
                    const float* __restrict__ bih_b, const float* __restrict__ bhh_b,
                    const float* __restrict__ W1, const float* __restrict__ b1,
                    const float* __restrict__ W2, const float* __restrict__ b2,
                    float* __restrict__ out)
{
  __shared__ float    xbuf[8][TT];       // staged input rows (16 KB)
  __shared__ unsigned hp[2][4][2][16];   // packed-pair h exchange, dbuf (1 KB)
  __shared__ float    obuf[8][64];       // [row][h_f(32) | h_b(32)] (2 KB)

  const int tid  = threadIdx.x;
  const int lane = tid & 63;
  const int wid  = tid >> 6;           // wave 0..3; serves block rows {2wid, 2wid+1}
  const int nh   = lane & 15;          // MFMA n-index
  const int q    = lane >> 4;          // quad 0..3
  const int p    = q & 1;              // owned element's row parity
  const int hsel = lane >> 5;          // owned element's j-half
  const int j    = nh + 16 * hsel;     // owned output column
  const int rs   = 2 * wid + p;        // owned element's local row (0..7)

  // --- stage 8 rows of X into LDS (32-lane groups, coalesced) ---
  const int g32 = tid & 31, rsS = tid >> 5;
  const vf4* Xr4 = (const vf4*)(X + (size_t)((blockIdx.x << 3) + rsS) * TT);
  vf4* xb4 = (vf4*)&xbuf[rsS][0];
  #pragma unroll
  for (int qq = 0; qq < 4; ++qq) xb4[g32 + 32 * qq] = Xr4[g32 + 32 * qq];

  const float s1 = -LOG2E;             // r,z: sigmoid domain (negated)
  const float s2 = 2.0f * LOG2E;       // n: tanh domain

  // --- B-fragments: W_hh, constant, PAIR-INTERLEAVED labeling (R20-proven):
  //     element order k = (4q, 16+4q, 4q+1, 16+4q+1, 4q+2, 16+4q+2, 4q+3, 16+4q+3)
  //     Gate G, j-half F: lane (nh,q) holds W[G*32 + nh + 16F][k] * S ---
#define LDB(P, G, F, S) h8 P; { \
    const float* wr = Whh_f + (size_t)((G)*HH + nh + 16*(F)) * HH; \
    const int k1 = 4*q, k2 = 16 + 4*q; \
    P = (h8){ (f16)(wr[k1  ]*(S)), (f16)(wr[k2  ]*(S)), \
              (f16)(wr[k1+1]*(S)), (f16)(wr[k2+1]*(S)), \
              (f16)(wr[k1+2]*(S)), (f16)(wr[k2+2]*(S)), \
              (f16)(wr[k1+3]*(S)), (f16)(wr[k2+3]*(S)) }; }
  LDB(Br0, 0, 0, s1); LDB(Br1, 0, 1, s1);
  LDB(Bz0, 1, 0, s1); LDB(Bz1, 1, 1, s1);
  LDB(Bn0, 2, 0, s2); LDB(Bn1, 2, 1, s2);

  // --- per-lane seed consts for the owned column j ---
  const float xwr = Wih_f[j] * s1, xwz = Wih_f[HH + j] * s1, xwn = Wih_f[2*HH + j] * s2;
  const float cbr = (bih_f[j]      + bhh_f[j])      * s1;
  const float cbz = (bih_f[HH + j] + bhh_f[HH + j]) * s1;
  const float cbn = bih_f[2*HH + j] * s2;        // n: b_ih term (with x)
  const float cbh = bhh_f[2*HH + j] * s2;        // n: b_hh term (inside r*(.)) -> C
  const vf4 Ch = { cbh, 0.0f, 0.0f, 0.0f };

  // --- exchange addresses (loop-invariant, compile-time parity select) ---
  //     A-frag read: row R=(lane>>2)&1, cols 4q..4q+3 -> one b128.
  //     write: own (p, col nh, half hsel) -> one b16.
  const int Rr = (lane >> 2) & 1;
  const h8* rp0 = (const h8*)&hp[0][wid][Rr][q << 2];
  const h8* rp1 = (const h8*)&hp[1][wid][Rr][q << 2];
  unsigned short* wp0 = (unsigned short*)&hp[0][wid][p][nh] + hsel;
  unsigned short* wp1 = (unsigned short*)&hp[1][wid][p][nh] + hsel;

  float h = 0.0f;
  *wp0 = 0; *wp1 = 0;                  // h0 = 0 in both parity buffers
  __builtin_amdgcn_wave_barrier();

  const vf4* xv = (const vf4*)&xbuf[rs][0];
  vf4 x4 = xv[0];

  #pragma unroll 1
  for (int tg = 0; tg < TT / 4; ++tg) {
    const vf4 x4n = xv[tg + 1 < TT / 4 ? tg + 1 : tg];   // off critical path

    // hoist x-dependent seeds for the 4 sub-steps (own row's x, own j)
    const float sr0 = __builtin_fmaf(x4.x, xwr, cbr), sz0 = __builtin_fmaf(x4.x, xwz, cbz),
                sn0 = __builtin_fmaf(x4.x, xwn, cbn);
    const float sr1 = __builtin_fmaf(x4.y, xwr, cbr), sz1 = __builtin_fmaf(x4.y, xwz, cbz),
                sn1 = __builtin_fmaf(x4.y, xwn, cbn);
    const float sr2 = __builtin_fmaf(x4.z, xwr, cbr), sz2 = __builtin_fmaf(x4.z, xwz, cbz),
                sn2 = __builtin_fmaf(x4.z, xwn, cbn);
    const float sr3 = __builtin_fmaf(x4.w, xwr, cbr), sz3 = __builtin_fmaf(x4.w, xwz, cbz),
                sn3 = __builtin_fmaf(x4.w, xwn, cbn);

    #pragma unroll
    for (int u = 0; u < 4; ++u) {
      const float sr = (u == 0) ? sr0 : (u == 1) ? sr1 : (u == 2) ? sr2 : sr3;
      const float sz = (u == 0) ? sz0 : (u == 1) ? sz1 : (u == 2) ? sz2 : sz3;
      const float sn = (u == 0) ? sn0 : (u == 1) ? sn1 : (u == 2) ? sn2 : sn3;

      // A-frag: ONE broadcast ds_read_b128 from the pair buffer (parity u&1)
      const h8 A = (u & 1) ? *rp1 : *rp0;

      // D = h @ W^T (+ per-lane seeds in C reg0): 6 MFMA, reg0 consumed
      const vf4 Cr = { sr, 0.0f, 0.0f, 0.0f };
      const vf4 Cz = { sz, 0.0f, 0.0f, 0.0f };
      const vf4 Dr0 = __builtin_amdgcn_mfma_f32_16x16x32_f16(A, Br0, Cr, 0, 0, 0);
      const vf4 Dr1 = __builtin_amdgcn_mfma_f32_16x16x32_f16(A, Br1, Cr, 0, 0, 0);
      const vf4 Dz0 = __builtin_amdgcn_mfma_f32_16x16x32_f16(A, Bz0, Cz, 0, 0, 0);
      const vf4 Dz1 = __builtin_amdgcn_mfma_f32_16x16x32_f16(A, Bz1, Cz, 0, 0, 0);
      const vf4 Dn0 = __builtin_amdgcn_mfma_f32_16x16x32_f16(A, Bn0, Ch, 0, 0, 0);
      const vf4 Dn1 = __builtin_amdgcn_mfma_f32_16x16x32_f16(A, Bn1, Ch, 0, 0, 0);

      // select own j-half: element (row p, col j), seeds already included
      const float ar = hsel ? Dr1[0] : Dr0[0];
      const float az = hsel ? Dz1[0] : Dz0[0];
      const float an = hsel ? Dn1[0] : Dn0[0];

      // epilogue (fused tail): z-path first, its consumers precomputed so a
      // single fma follows the last rcp on the critical chain
      const float z    = __builtin_amdgcn_rcpf(1.0f + __builtin_amdgcn_exp2f(az));
      const float omz  = 1.0f - z;
      const float base = __builtin_fmaf(z, h, omz);        // z*h + (1-z)
      const float m2   = __builtin_fmaf(2.0f, z, -2.0f);   // -2*(1-z)
      const float r    = __builtin_amdgcn_rcpf(1.0f + __builtin_amdgcn_exp2f(ar));
      const float y    = __builtin_fmaf(r, an, sn);
      const float w    = __builtin_amdgcn_rcpf(1.0f + __builtin_amdgcn_exp2f(y));
      h = __builtin_fmaf(m2, w, base);   // (1-z)*(1-2w) + z*h

      // write own f16 into the OPPOSITE parity buffer (for step u+1)
      union { f16 f; unsigned short u16; } cc; cc.f = (f16)h;
      if (u & 1) *wp0 = cc.u16; else *wp1 = cc.u16;
      __builtin_amdgcn_wave_barrier();   // wave-synchronous ordering
    }
    x4 = x4n;
  }

  // --- publish h_f (fp32): each lane writes its (row, j) element once ---
  obuf[rs][j] = h;
  __syncthreads();

  // --- backward direction: exactly ONE GRU step from h0=0 on x[T-1] ---
  const float xl  = xbuf[rsS][TT - 1];
  const float rbv = fast_sigm(__builtin_fmaf(xl, Wih_b[g32],      bih_b[g32]      + bhh_b[g32]));
  const float zbv = fast_sigm(__builtin_fmaf(xl, Wih_b[HH + g32], bih_b[HH + g32] + bhh_b[HH + g32]));
  const float xnb = __builtin_fmaf(xl, Wih_b[2*HH + g32], bih_b[2*HH + g32]);
  const float nbv = fast_tanh(__builtin_fmaf(rbv, bhh_b[2*HH + g32], xnb));
  const float hbv = nbv - zbv * nbv;             // (1-zb)*nb + zb*0

  obuf[rsS][32 + g32] = hbv;                     // h_b
  __builtin_amdgcn_wave_barrier();

  // --- MLP head: sigmoid(W2 @ relu(W1 @ [h_f,h_b] + b1) + b2) ---
  const int jj = g32 & 15;                       // lanes 16..31 duplicate
  const vf4* W1r = (const vf4*)(W1 + jj * 64);
  const vf4* hc  = (const vf4*)&obuf[rsS][0];
  vf4 a4 = W1r[0] * hc[0];
  #pragma unroll
  for (int qq = 1; qq < 16; ++qq)
    a4 = __builtin_elementwise_fma(W1r[qq], hc[qq], a4);
  float acc = b1[jj] + (a4.x + a4.y) + (a4.z + a4.w);
  float h1v = fmaxf(acc, 0.0f) * W2[jj];
  h1v += __shfl_down(h1v, 8, 16);
  h1v += __shfl_down(h1v, 4, 16);
  h1v += __shfl_down(h1v, 2, 16);
  h1v += __shfl_down(h1v, 1, 16);
  if (g32 == 0) out[(blockIdx.x << 3) + rsS] = fast_sigm(h1v + b2[0]);
}

extern "C" void kernel_launch(void* const* d_in, const int* in_sizes, int n_in,
                              void* d_out, int out_size, void* d_ws, size_t ws_size,
                              hipStream_t stream) {
  const float* X     = (const float*)d_in[0];
  const float* Wih_f = (const float*)d_in[1];
  const float* Whh_f = (const float*)d_in[2];
  const float* bih_f = (const float*)d_in[3];
  const float* bhh_f = (const float*)d_in[4];
  const float* Wih_b = (const float*)d_in[5];
  // d_in[6] = W_hh_b: unused — backward direction runs exactly one step from h0=0.
  const float* bih_b = (const float*)d_in[7];
  const float* bhh_b = (const float*)d_in[8];
  const float* W1    = (const float*)d_in[9];
  const float* b1    = (const float*)d_in[10];
  const float* W2    = (const float*)d_in[11];
  const float* b2    = (const float*)d_in[12];
  float* out = (float*)d_out;

  // 2048 rows / 8 rows per 256-thread block = 256 blocks = 1 block/CU,
  // 1024 independent waves = 1 wave/SIMD, full chip. Exchange is one
  // ds_write_b16 + one broadcast ds_read_b128 (pair layout), wave-internal.
  gru_bidir_head<<<256, 256, 0, stream>>>(X, Wih_f, Whh_f, bih_f, bhh_f,
                                          Wih_b, bih_b, bhh_b, W1, b1, W2, b2, out);
}